// Round 1
// baseline (143.021 us; speedup 1.0000x reference)
//
#include <hip/hip_runtime.h>

// Problem constants (from reference): B=2048, C=64, IN=512, OUT=512
// out[b, o] = sum_k weight[index[b], o, k] * x[b, k]
//
// Design: grid = C(64) x OUT-tiles(8, OT=64) = 512 blocks, 256 threads.
// Each block: scan index[] -> LDS list of its class's samples; then tiled
// fp32 GEMM over sample-tiles of ST=32, K-chunks of KT=64.
// W tile stored transposed (Wl[k][o], pad +4 for 16B-aligned float4 reads).

constexpr int Bsz = 2048;
constexpr int Ccnt = 64;
constexpr int INF = 512;
constexpr int OUTF = 512;
constexpr int OT = 64;   // out rows per block
constexpr int ST = 32;   // samples per tile
constexpr int KT = 64;   // k per chunk
constexpr int NTO = OUTF / OT;  // 8
constexpr int THREADS = 256;

__global__ __launch_bounds__(THREADS)
void switching_linear_kernel(const float* __restrict__ x,
                             const int* __restrict__ idx,
                             const float* __restrict__ w,
                             float* __restrict__ out) {
    __shared__ unsigned short list[Bsz];   // 4 KB
    __shared__ int ls_n;
    __shared__ float Wl[KT][OT + 4];       // 64*68*4 = 17 KB, transposed W tile
    __shared__ float Xl[KT][ST + 2];       // 64*34*4 = 8.5 KB

    const int tid = threadIdx.x;
    const int c  = blockIdx.x >> 3;        // class
    const int o0 = (blockIdx.x & 7) * OT;  // out-row base

    if (tid == 0) ls_n = 0;
    __syncthreads();

    // Build per-class sample list (order irrelevant)
    for (int i = tid; i < Bsz; i += THREADS) {
        if (idx[i] == c) {
            int p = atomicAdd(&ls_n, 1);
            list[p] = (unsigned short)i;
        }
    }
    __syncthreads();
    const int n = ls_n;

    // thread tile: 2 samples x 4 outs
    const int sy = tid >> 4;   // 0..15 -> samples 2sy, 2sy+1
    const int og = tid & 15;   // 0..15 -> outs 4og..4og+3

    const float* wc = w + (size_t)c * OUTF * INF + (size_t)o0 * INF;

    // W-loader mapping: o = tid>>2 (0..63), k base = (tid&3)*16, 16 floats/thread
    const int wl_o  = tid >> 2;
    const int wl_kb = (tid & 3) * 16;
    // X-loader mapping: s = tid>>3 (0..31), k base = (tid&7)*8, 8 floats/thread
    const int xl_s  = tid >> 3;
    const int xl_kb = (tid & 7) * 8;

    for (int s0 = 0; s0 < n; s0 += ST) {
        float acc[2][4] = {{0.f, 0.f, 0.f, 0.f}, {0.f, 0.f, 0.f, 0.f}};

        for (int kt = 0; kt < INF; kt += KT) {
            // ---- stage W tile (transpose into Wl[k][o]) ----
            {
                const float* src = wc + (size_t)wl_o * INF + kt + wl_kb;
#pragma unroll
                for (int j = 0; j < 4; ++j) {
                    float4 v = *(const float4*)(src + 4 * j);
                    int k = wl_kb + 4 * j;
                    Wl[k + 0][wl_o] = v.x;
                    Wl[k + 1][wl_o] = v.y;
                    Wl[k + 2][wl_o] = v.z;
                    Wl[k + 3][wl_o] = v.w;
                }
            }
            // ---- stage X tile ----
            {
                const int sg = s0 + xl_s;
                if (sg < n) {
                    const float* src = x + (size_t)list[sg] * INF + kt + xl_kb;
#pragma unroll
                    for (int j = 0; j < 2; ++j) {
                        float4 v = *(const float4*)(src + 4 * j);
                        int k = xl_kb + 4 * j;
                        Xl[k + 0][xl_s] = v.x;
                        Xl[k + 1][xl_s] = v.y;
                        Xl[k + 2][xl_s] = v.z;
                        Xl[k + 3][xl_s] = v.w;
                    }
                } else {
#pragma unroll
                    for (int j = 0; j < 8; ++j) Xl[xl_kb + j][xl_s] = 0.f;
                }
            }
            __syncthreads();

            // ---- compute: 2 samples x 4 outs per thread ----
#pragma unroll
            for (int k = 0; k < KT; ++k) {
                float xa = Xl[k][2 * sy];
                float xb = Xl[k][2 * sy + 1];
                float4 wv = *(const float4*)&Wl[k][4 * og];
                acc[0][0] += xa * wv.x;
                acc[0][1] += xa * wv.y;
                acc[0][2] += xa * wv.z;
                acc[0][3] += xa * wv.w;
                acc[1][0] += xb * wv.x;
                acc[1][1] += xb * wv.y;
                acc[1][2] += xb * wv.z;
                acc[1][3] += xb * wv.w;
            }
            __syncthreads();
        }

        // ---- store (guard padding samples) ----
#pragma unroll
        for (int ss = 0; ss < 2; ++ss) {
            int sg = s0 + 2 * sy + ss;
            if (sg < n) {
                float* dst = out + (size_t)list[sg] * OUTF + o0 + 4 * og;
                float4 v = make_float4(acc[ss][0], acc[ss][1], acc[ss][2], acc[ss][3]);
                *(float4*)dst = v;
            }
        }
    }
}

extern "C" void kernel_launch(void* const* d_in, const int* in_sizes, int n_in,
                              void* d_out, int out_size, void* d_ws, size_t ws_size,
                              hipStream_t stream) {
    const float* x   = (const float*)d_in[0];
    const int*   idx = (const int*)d_in[1];
    const float* w   = (const float*)d_in[2];
    float* out = (float*)d_out;

    dim3 grid(Ccnt * NTO);  // 512 blocks
    dim3 block(THREADS);
    switching_linear_kernel<<<grid, block, 0, stream>>>(x, idx, w, out);
}

// Round 2
// 125.049 us; speedup vs baseline: 1.1437x; 1.1437x over previous
//
#include <hip/hip_runtime.h>

// out[b, o] = sum_k weight[index[b], o, k] * x[b, k]
// B=2048, C=64, IN=OUT=512.
//
// Grid: 64 classes x 8 out-tiles(64 rows) = 512 blocks x 256 threads (4 waves).
// Each wave independently computes a 16(out) x 64(samples) tile with
// mfma_f32_16x16x32_bf16, streaming W and x straight from global memory into
// registers (fp32 -> bf16 RNE in-reg). No __syncthreads in the hot loop.
// N-tile=64 covers any realistic n_c in one pass -> every block streams its
// 32 KB W slice exactly once -> balanced, HBM-bound.

constexpr int Bsz  = 2048;
constexpr int Ccnt = 64;
constexpr int INF  = 512;
constexpr int OUTF = 512;
constexpr int THREADS = 256;   // 4 waves
constexpr int OT = 64;         // out rows per block (16 per wave)
constexpr int NT = 64;         // sample tile (4 groups of 16)

typedef __attribute__((ext_vector_type(8))) short bf16x8;
typedef __attribute__((ext_vector_type(4))) float f32x4;

__device__ __forceinline__ unsigned short f2bf(float f) {
    union { float f; unsigned u; } v; v.f = f;
    // round-to-nearest-even fp32 -> bf16 (inputs are finite, no NaN handling)
    return (unsigned short)((v.u + 0x7FFFu + ((v.u >> 16) & 1u)) >> 16);
}

__global__ __launch_bounds__(THREADS)
void switching_linear_kernel(const float* __restrict__ x,
                             const int* __restrict__ idx,
                             const float* __restrict__ w,
                             float* __restrict__ out) {
    __shared__ unsigned short list[Bsz];  // 4 KB
    __shared__ int ls_n;

    const int tid = threadIdx.x;
    const int c  = blockIdx.x >> 3;         // class
    const int o0 = (blockIdx.x & 7) * OT;   // block's out-row base

    if (tid == 0) ls_n = 0;
    __syncthreads();
    for (int i = tid; i < Bsz; i += THREADS) {
        if (idx[i] == c) list[atomicAdd(&ls_n, 1)] = (unsigned short)i;
    }
    __syncthreads();
    const int n = ls_n;
    if (n == 0) return;

    const int wave = tid >> 6;     // 0..3
    const int lane = tid & 63;
    const int mrow = lane & 15;    // A row / B col / C col
    const int quad = lane >> 4;    // 0..3 -> k segment (quad*8) / C row group
    const int ow   = o0 + wave * 16;

    // A fragment source: w[c][ow+mrow][quad*8 + j + kt], j=0..7 (32 B contiguous)
    const float* aptr = w + ((size_t)c * OUTF + (size_t)(ow + mrow)) * INF + quad * 8;

    for (int s0 = 0; s0 < n; s0 += NT) {
        // per-group sample pointers (per-lane: sample = s0 + 16g + mrow)
        const float* bptr[4];
        bool bval[4];
#pragma unroll
        for (int g = 0; g < 4; ++g) {
            int s = s0 + g * 16 + mrow;
            bval[g] = (s < n);
            int b = bval[g] ? (int)list[s] : 0;
            bptr[g] = x + (size_t)b * INF + quad * 8;
        }

        f32x4 acc[4] = {{0.f,0.f,0.f,0.f},{0.f,0.f,0.f,0.f},
                        {0.f,0.f,0.f,0.f},{0.f,0.f,0.f,0.f}};

#pragma unroll 2
        for (int kt = 0; kt < INF; kt += 32) {
            // ---- A fragment: 8 consecutive k of this lane's out row ----
            float4 a0 = *(const float4*)(aptr + kt);
            float4 a1 = *(const float4*)(aptr + kt + 4);
            bf16x8 af;
            af[0] = (short)f2bf(a0.x); af[1] = (short)f2bf(a0.y);
            af[2] = (short)f2bf(a0.z); af[3] = (short)f2bf(a0.w);
            af[4] = (short)f2bf(a1.x); af[5] = (short)f2bf(a1.y);
            af[6] = (short)f2bf(a1.z); af[7] = (short)f2bf(a1.w);

#pragma unroll
            for (int g = 0; g < 4; ++g) {
                bf16x8 bf = {0,0,0,0,0,0,0,0};
                if (bval[g]) {
                    float4 b0 = *(const float4*)(bptr[g] + kt);
                    float4 b1 = *(const float4*)(bptr[g] + kt + 4);
                    bf[0] = (short)f2bf(b0.x); bf[1] = (short)f2bf(b0.y);
                    bf[2] = (short)f2bf(b0.z); bf[3] = (short)f2bf(b0.w);
                    bf[4] = (short)f2bf(b1.x); bf[5] = (short)f2bf(b1.y);
                    bf[6] = (short)f2bf(b1.z); bf[7] = (short)f2bf(b1.w);
                }
                acc[g] = __builtin_amdgcn_mfma_f32_16x16x32_bf16(af, bf, acc[g], 0, 0, 0);
            }
        }

        // ---- store: C col = mrow (sample), C row = quad*4 + reg (out) ----
#pragma unroll
        for (int g = 0; g < 4; ++g) {
            int s = s0 + g * 16 + mrow;
            if (s < n) {
                int b = (int)list[s];
                float* dst = out + (size_t)b * OUTF + ow + quad * 4;
                *(float4*)dst = make_float4(acc[g][0], acc[g][1], acc[g][2], acc[g][3]);
            }
        }
    }
}

extern "C" void kernel_launch(void* const* d_in, const int* in_sizes, int n_in,
                              void* d_out, int out_size, void* d_ws, size_t ws_size,
                              hipStream_t stream) {
    const float* x   = (const float*)d_in[0];
    const int*   idx = (const int*)d_in[1];
    const float* w   = (const float*)d_in[2];
    float* out = (float*)d_out;

    dim3 grid(Ccnt * (OUTF / OT));  // 512
    dim3 block(THREADS);
    switching_linear_kernel<<<grid, block, 0, stream>>>(x, idx, w, out);
}

// Round 3
// 121.693 us; speedup vs baseline: 1.1753x; 1.0276x over previous
//
#include <hip/hip_runtime.h>

// out[b, o] = sum_k weight[index[b], o, k] * x[b, k];  B=2048, C=64, IN=OUT=512.
//
// Grid: 64 classes x 16 row-tiles(OT=32) = 1024 blocks x 256 threads (4 waves)
//   wave w: r = w&1 -> rows [o0+16r, +16), kh = w>>1 -> K half [256*kh, +256).
// Each wave: 16(out) x 64(samples) MFMA tile over its K half, streaming W/x
// from global (L3-resident after first pass) into registers, fp32->bf16
// packed cvt. K-half partials combined through LDS (deterministic, no global
// atomics). No barrier in the K loop. Empty 16-sample groups are skipped.
// 1024 blocks -> 4 blocks/CU -> 16 waves/CU (50% occupancy ceiling).

constexpr int Bsz  = 2048;
constexpr int Ccnt = 64;
constexpr int INF  = 512;
constexpr int OUTF = 512;
constexpr int THREADS = 256;
constexpr int OT = 32;                     // out rows per block
constexpr int NT = 64;                     // sample tile
constexpr int NBLK = Ccnt * (OUTF / OT);   // 1024

typedef __attribute__((ext_vector_type(8))) short bf16x8;
typedef __attribute__((ext_vector_type(4))) float f32x4;

#if __has_builtin(__builtin_amdgcn_cvt_pk_bf16_f32)
typedef __attribute__((ext_vector_type(2))) __bf16 bf16x2_t;
__device__ __forceinline__ int cvt2i(float a, float b) {
    union { bf16x2_t v; int i; } u;
    u.v = __builtin_amdgcn_cvt_pk_bf16_f32(a, b);
    return u.i;
}
#else
__device__ __forceinline__ unsigned f2bf(float f) {
    union { float f; unsigned u; } v; v.f = f;
    return (v.u + 0x7FFFu + ((v.u >> 16) & 1u)) >> 16;   // RNE
}
__device__ __forceinline__ int cvt2i(float a, float b) {
    return (int)(f2bf(a) | (f2bf(b) << 16));
}
#endif

__device__ __forceinline__ bf16x8 cvt8(float4 a, float4 b) {
    union { bf16x8 v; int i[4]; } u;
    u.i[0] = cvt2i(a.x, a.y);
    u.i[1] = cvt2i(a.z, a.w);
    u.i[2] = cvt2i(b.x, b.y);
    u.i[3] = cvt2i(b.z, b.w);
    return u.v;
}

__global__ __launch_bounds__(THREADS, 4)
void switching_linear_kernel(const float* __restrict__ x,
                             const int* __restrict__ idx,
                             const float* __restrict__ w,
                             float* __restrict__ out) {
    __shared__ unsigned short list[Bsz];   // 4 KB
    __shared__ int ls_n;
    __shared__ float red[2][16][64];       // 8 KB, lane-major (conflict-free)

    const int tid = threadIdx.x;
    const int c  = blockIdx.x >> 4;          // class
    const int o0 = (blockIdx.x & 15) * OT;   // block's out-row base

    if (tid == 0) ls_n = 0;
    __syncthreads();
    for (int i = tid; i < Bsz; i += THREADS) {
        if (idx[i] == c) list[atomicAdd(&ls_n, 1)] = (unsigned short)i;
    }
    __syncthreads();
    const int n = ls_n;
    if (n == 0) return;

    const int wave = tid >> 6;
    const int lane = tid & 63;
    const int r    = wave & 1;      // row-group within block
    const int kh   = wave >> 1;     // K half
    const int mrow = lane & 15;     // A row / B col / C col
    const int quad = lane >> 4;     // k segment (quad*8) / C row group
    const int ow   = o0 + r * 16;
    const int k0   = kh * (INF / 2);

    // A source: w[c][ow+mrow][k0 + quad*8 + ...]
    const float* aptr = w + ((size_t)c * OUTF + (size_t)(ow + mrow)) * INF
                          + k0 + quad * 8;

    for (int s0 = 0; s0 < n; s0 += NT) {
        const int rem = n - s0;
        const int ng  = rem >= NT ? 4 : (rem + 15) >> 4;   // active 16-sample groups

        const float* bptr[4];
        bool bval[4];
#pragma unroll
        for (int g = 0; g < 4; ++g) {
            int s = s0 + g * 16 + mrow;
            bval[g] = (s < n);
            int b = bval[g] ? (int)list[s] : 0;
            bptr[g] = x + (size_t)b * INF + k0 + quad * 8;
        }

        f32x4 acc[4] = {{0.f,0.f,0.f,0.f},{0.f,0.f,0.f,0.f},
                        {0.f,0.f,0.f,0.f},{0.f,0.f,0.f,0.f}};

#pragma unroll 4
        for (int kt = 0; kt < INF / 2; kt += 32) {
            float4 a0 = *(const float4*)(aptr + kt);
            float4 a1 = *(const float4*)(aptr + kt + 4);
            bf16x8 af = cvt8(a0, a1);

            for (int g = 0; g < ng; ++g) {
                bf16x8 bfr = {0,0,0,0,0,0,0,0};
                if (bval[g]) {
                    float4 b0 = *(const float4*)(bptr[g] + kt);
                    float4 b1 = *(const float4*)(bptr[g] + kt + 4);
                    bfr = cvt8(b0, b1);
                }
                acc[g] = __builtin_amdgcn_mfma_f32_16x16x32_bf16(af, bfr, acc[g], 0, 0, 0);
            }
        }

        // ---- combine K halves through LDS, kh==0 waves store ----
        if (kh == 1) {
#pragma unroll
            for (int g = 0; g < 4; ++g) {
                if (g < ng) {
#pragma unroll
                    for (int j = 0; j < 4; ++j) red[r][g * 4 + j][lane] = acc[g][j];
                }
            }
        }
        __syncthreads();
        if (kh == 0) {
#pragma unroll
            for (int g = 0; g < 4; ++g) {
                if (g < ng) {
                    int s = s0 + g * 16 + mrow;
                    if (s < n) {
                        float4 v;
                        v.x = acc[g][0] + red[r][g * 4 + 0][lane];
                        v.y = acc[g][1] + red[r][g * 4 + 1][lane];
                        v.z = acc[g][2] + red[r][g * 4 + 2][lane];
                        v.w = acc[g][3] + red[r][g * 4 + 3][lane];
                        float* dst = out + (size_t)list[s] * OUTF + ow + quad * 4;
                        *(float4*)dst = v;
                    }
                }
            }
        }
        __syncthreads();   // red reusable next s0 pass
    }
}

extern "C" void kernel_launch(void* const* d_in, const int* in_sizes, int n_in,
                              void* d_out, int out_size, void* d_ws, size_t ws_size,
                              hipStream_t stream) {
    const float* x   = (const float*)d_in[0];
    const int*   idx = (const int*)d_in[1];
    const float* w   = (const float*)d_in[2];
    float* out = (float*)d_out;

    switching_linear_kernel<<<dim3(NBLK), dim3(THREADS), 0, stream>>>(x, idx, w, out);
}

// Round 4
// 116.490 us; speedup vs baseline: 1.2278x; 1.0447x over previous
//
#include <hip/hip_runtime.h>

// out[b, o] = sum_k weight[index[b], o, k] * x[b, k];  B=2048, C=64, IN=OUT=512.
//
// Streaming design: block = (class c, 32 out-rows), 1024 blocks x 256 thr (4 waves).
// Entire 64 KB W-slice async-staged to LDS via global_load_lds dwordx4 (64 insts,
// issued before any wait -> ~128 KB/CU outstanding, saturates HBM). Staging
// permutes 16B granules so compute reads A-fragments as contiguous ds_read_b128.
// Wave w = sample group (16 samples), full K=512, 2 MFMA tiles (32 rows)/kt.

constexpr int Bsz  = 2048;
constexpr int Ccnt = 64;
constexpr int INF  = 512;
constexpr int OUTF = 512;
constexpr int THREADS = 256;   // 4 waves
constexpr int OT = 32;         // out rows per block
constexpr int NT = 64;         // samples per pass (4 waves x 16)
constexpr int NBLK = Ccnt * (OUTF / OT);   // 1024

typedef __attribute__((ext_vector_type(8))) short bf16x8;
typedef __attribute__((ext_vector_type(4))) float f32x4;

#if __has_builtin(__builtin_amdgcn_cvt_pk_bf16_f32)
typedef __attribute__((ext_vector_type(2))) __bf16 bf16x2_t;
__device__ __forceinline__ int cvt2i(float a, float b) {
    union { bf16x2_t v; int i; } u;
    u.v = __builtin_amdgcn_cvt_pk_bf16_f32(a, b);
    return u.i;
}
#else
__device__ __forceinline__ unsigned f2bf(float f) {
    union { float f; unsigned u; } v; v.f = f;
    return (v.u + 0x7FFFu + ((v.u >> 16) & 1u)) >> 16;   // RNE
}
__device__ __forceinline__ int cvt2i(float a, float b) {
    return (int)(f2bf(a) | (f2bf(b) << 16));
}
#endif

__device__ __forceinline__ bf16x8 cvt8(float4 a, float4 b) {
    union { bf16x8 v; int i[4]; } u;
    u.i[0] = cvt2i(a.x, a.y);
    u.i[1] = cvt2i(a.z, a.w);
    u.i[2] = cvt2i(b.x, b.y);
    u.i[3] = cvt2i(b.z, b.w);
    return u.v;
}

// async 16B/lane global -> LDS (dest = wave-uniform base + lane*16)
__device__ __forceinline__ void gld_lds16(const float* g, float* l) {
    __builtin_amdgcn_global_load_lds(
        (const __attribute__((address_space(1))) float*)g,
        (__attribute__((address_space(3))) float*)l, 16, 0, 0);
}

__global__ __launch_bounds__(THREADS, 2)
void switching_linear_kernel(const float* __restrict__ x,
                             const int* __restrict__ idx,
                             const float* __restrict__ w,
                             float* __restrict__ out) {
    __shared__ float Wl[OT * INF];         // 64 KB, swizzled 2KB chunks
    __shared__ unsigned short list[Bsz];   // 4 KB
    __shared__ int ls_n;

    const int tid  = threadIdx.x;
    const int wave = tid >> 6;
    const int lane = tid & 63;
    const int c  = blockIdx.x >> 4;          // class
    const int o0 = (blockIdx.x & 15) * OT;   // out-row base

    if (tid == 0) ls_n = 0;
    __syncthreads();   // before any staging is outstanding (cheap drain)

    // (1) idx slice -> regs (issued before staging so its wait leaves staging in flight)
    int myidx[8];
#pragma unroll
    for (int i = 0; i < 8; ++i) myidx[i] = idx[tid + i * THREADS];

    // (2) issue all W staging: 64 x 1KB, 16 insts per wave, no waits.
    // LDS layout: chunk ci = r*16 + kt32 (2KB = 16 rows x 32 k), position
    // p = h*64 + lane holds granule (row = (p/2)&15, gk = 2*((p/2)>>4) + (p&1)),
    // so compute lane L reads its A-frag (row = L&15, k = (L>>4)*8..+8) at
    // chunk float offset L*8 -> contiguous ds_read_b128 x2, conflict-free.
    const float* wc = w + (size_t)c * OUTF * INF + (size_t)o0 * INF;
#pragma unroll
    for (int i = 0; i < 16; ++i) {
        const int inst = wave * 16 + i;
        const int ci = inst >> 1;                  // 0..31
        const int h  = inst & 1;
        const int p  = h * 64 + lane;
        const int l  = p >> 1;
        const int row = (ci >> 4) * 16 + (l & 15);
        const int gk  = 2 * (l >> 4) + (p & 1);
        const float* src = wc + (size_t)row * INF + (ci & 15) * 32 + gk * 4;
        gld_lds16(src, &Wl[ci * 512 + h * 256]);   // uniform base per inst
    }

    // (3) list build (overlaps with staging in flight)
#pragma unroll
    for (int i = 0; i < 8; ++i) {
        if (myidx[i] == c) list[atomicAdd(&ls_n, 1)] = (unsigned short)(tid + i * THREADS);
    }

    __syncthreads();   // W in LDS (compiler drains vmcnt) + list complete
    const int n = ls_n;

    const int mrow = lane & 15;   // sample col / C col
    const int quad = lane >> 4;   // k segment / C row group
    const int lofs = lane * 8;    // A-frag float offset within chunk

    for (int s0 = 0; s0 < n; s0 += NT) {
        if (s0 + wave * 16 >= n) break;        // whole group empty
        const int s = s0 + wave * 16 + mrow;
        const bool v = (s < n);
        const float* bp = x + (size_t)(v ? (int)list[s] : 0) * INF + quad * 8;

        f32x4 acc0 = {0.f,0.f,0.f,0.f}, acc1 = {0.f,0.f,0.f,0.f};

#pragma unroll 4
        for (int kt32 = 0; kt32 < 16; ++kt32) {
            const float* ch0 = &Wl[kt32 * 512 + lofs];          // rows o0..o0+16
            const float* ch1 = &Wl[(16 + kt32) * 512 + lofs];   // rows o0+16..+32
            float4 a00 = *(const float4*)ch0;
            float4 a01 = *(const float4*)(ch0 + 4);
            float4 a10 = *(const float4*)ch1;
            float4 a11 = *(const float4*)(ch1 + 4);

            bf16x8 bfr = {0,0,0,0,0,0,0,0};
            if (v) {
                float4 b0 = *(const float4*)(bp + kt32 * 32);
                float4 b1 = *(const float4*)(bp + kt32 * 32 + 4);
                bfr = cvt8(b0, b1);
            }
            acc0 = __builtin_amdgcn_mfma_f32_16x16x32_bf16(cvt8(a00, a01), bfr, acc0, 0, 0, 0);
            acc1 = __builtin_amdgcn_mfma_f32_16x16x32_bf16(cvt8(a10, a11), bfr, acc1, 0, 0, 0);
        }

        if (v) {
            // C: col = mrow (sample), row = quad*4 + j (out)
            float* d0 = out + (size_t)list[s] * OUTF + o0 + quad * 4;
            *(float4*)d0 = make_float4(acc0[0], acc0[1], acc0[2], acc0[3]);
            *(float4*)(d0 + 16) = make_float4(acc1[0], acc1[1], acc1[2], acc1[3]);
        }
    }
}

extern "C" void kernel_launch(void* const* d_in, const int* in_sizes, int n_in,
                              void* d_out, int out_size, void* d_ws, size_t ws_size,
                              hipStream_t stream) {
    const float* x   = (const float*)d_in[0];
    const int*   idx = (const int*)d_in[1];
    const float* w   = (const float*)d_in[2];
    float* out = (float*)d_out;

    switching_linear_kernel<<<dim3(NBLK), dim3(THREADS), 0, stream>>>(x, idx, w, out);
}

// Round 5
// 113.316 us; speedup vs baseline: 1.2621x; 1.0280x over previous
//
#include <hip/hip_runtime.h>

// out[b, o] = sum_k weight[index[b], o, k] * x[b, k];  B=2048, C=64, IN=OUT=512.
//
// Latency-first design (r2-r4 plateaued at ~42us with every pipe idle ->
// phase serialization, not BW, was binding):
//   grid = 64 classes x 32 row-tiles(OT=16) = 2048 blocks x 256 thr.
//   wave = K-quarter (128). Every wave has work for any n>0 (no idle waves).
//   W never touches LDS: each wave's A-fragments = 8 independent float4
//   register loads issued at block start (address = f(blockIdx) only).
//   idx loads issued alongside; scan overlaps W flight. x loads per
//   16-sample group are 8 independent float4. K-partials reduced via a
//   small lane-major LDS buffer (fixed order w1+w2+w3 -> deterministic).

constexpr int Bsz  = 2048;
constexpr int Ccnt = 64;
constexpr int INF  = 512;
constexpr int OUTF = 512;
constexpr int THREADS = 256;   // 4 waves = 4 K-quarters
constexpr int OT = 16;         // out rows per block
constexpr int NBLK = Ccnt * (OUTF / OT);   // 2048

typedef __attribute__((ext_vector_type(8))) short bf16x8;
typedef __attribute__((ext_vector_type(4))) float f32x4;

#if __has_builtin(__builtin_amdgcn_cvt_pk_bf16_f32)
typedef __attribute__((ext_vector_type(2))) __bf16 bf16x2_t;
__device__ __forceinline__ int cvt2i(float a, float b) {
    union { bf16x2_t v; int i; } u;
    u.v = __builtin_amdgcn_cvt_pk_bf16_f32(a, b);
    return u.i;
}
#else
__device__ __forceinline__ unsigned f2bf(float f) {
    union { float f; unsigned u; } v; v.f = f;
    return (v.u + 0x7FFFu + ((v.u >> 16) & 1u)) >> 16;   // RNE
}
__device__ __forceinline__ int cvt2i(float a, float b) {
    return (int)(f2bf(a) | (f2bf(b) << 16));
}
#endif

__device__ __forceinline__ bf16x8 cvt8(float4 a, float4 b) {
    union { bf16x8 v; int i[4]; } u;
    u.i[0] = cvt2i(a.x, a.y);
    u.i[1] = cvt2i(a.z, a.w);
    u.i[2] = cvt2i(b.x, b.y);
    u.i[3] = cvt2i(b.z, b.w);
    return u.v;
}

__global__ __launch_bounds__(THREADS, 3)
void switching_linear_kernel(const float* __restrict__ x,
                             const int* __restrict__ idx,
                             const float* __restrict__ w,
                             float* __restrict__ out) {
    __shared__ unsigned short list[Bsz];    // 4 KB
    __shared__ int ls_n;
    __shared__ float red[4][3][4][64];      // 12 KB, lane-major (conflict-free)

    const int tid  = threadIdx.x;
    const int wave = tid >> 6;
    const int lane = tid & 63;
    const int c  = blockIdx.x >> 5;           // class
    const int o0 = (blockIdx.x & 31) * OT;    // out-row base
    const int mrow = lane & 15;               // A row / B col / C col
    const int quad = lane >> 4;               // k segment / C row group
    const int k0   = wave * (INF / 4);        // this wave's K-quarter

    if (tid == 0) ls_n = 0;
    __syncthreads();   // nothing in flight yet -> cheap

    // (1) idx slice -> regs (issued first; its wait leaves W loads in flight)
    int my[8];
#pragma unroll
    for (int i = 0; i < 8; ++i) my[i] = idx[tid + i * THREADS];

    // (2) this wave's entire W need: 8 independent float4 loads, no LDS
    const float* aptr = w + ((size_t)c * OUTF + (size_t)(o0 + mrow)) * INF
                          + k0 + quad * 8;
    float4 wv[8];
#pragma unroll
    for (int i = 0; i < 8; ++i)
        wv[i] = *(const float4*)(aptr + (i >> 1) * 32 + (i & 1) * 4);

    // (3) scan overlaps W flight
#pragma unroll
    for (int i = 0; i < 8; ++i)
        if (my[i] == c) list[atomicAdd(&ls_n, 1)] = (unsigned short)(tid + i * THREADS);

    __syncthreads();   // list ready (W drained here too)
    const int n = ls_n;

    // (4) W -> bf16 A-fragments, once; reused across all sample groups
    bf16x8 wf[4];
#pragma unroll
    for (int i = 0; i < 4; ++i) wf[i] = cvt8(wv[2 * i], wv[2 * i + 1]);

    for (int s0 = 0; s0 < n; s0 += 64) {
        const int rem = n - s0;
        const int ng  = rem >= 64 ? 4 : (rem + 15) >> 4;

        f32x4 acc[4];
#pragma unroll
        for (int g = 0; g < 4; ++g) acc[g] = (f32x4){0.f, 0.f, 0.f, 0.f};

#pragma unroll 2
        for (int g = 0; g < ng; ++g) {
            const int s = s0 + g * 16 + mrow;
            const bool v = (s < n);
            const float* bp = x + (size_t)(v ? (int)list[s] : 0) * INF + k0 + quad * 8;
            bf16x8 xf[4];
            if (v) {
#pragma unroll
                for (int i = 0; i < 4; ++i) {
                    float4 b0 = *(const float4*)(bp + i * 32);
                    float4 b1 = *(const float4*)(bp + i * 32 + 4);
                    xf[i] = cvt8(b0, b1);
                }
            } else {
#pragma unroll
                for (int i = 0; i < 4; ++i) xf[i] = (bf16x8){0,0,0,0,0,0,0,0};
            }
#pragma unroll
            for (int i = 0; i < 4; ++i)
                acc[g] = __builtin_amdgcn_mfma_f32_16x16x32_bf16(wf[i], xf[i], acc[g], 0, 0, 0);
        }

        // ---- K-reduce across the 4 waves (fixed order -> deterministic) ----
        if (wave != 0) {
#pragma unroll
            for (int g = 0; g < 4; ++g) {
                if (g < ng) {
#pragma unroll
                    for (int j = 0; j < 4; ++j) red[g][wave - 1][j][lane] = acc[g][j];
                }
            }
        }
        __syncthreads();
        if (wave == 0) {
#pragma unroll
            for (int g = 0; g < 4; ++g) {
                if (g < ng) {
                    const int s = s0 + g * 16 + mrow;
                    if (s < n) {
                        f32x4 a = acc[g];
#pragma unroll
                        for (int wv2 = 0; wv2 < 3; ++wv2)
#pragma unroll
                            for (int j = 0; j < 4; ++j) a[j] += red[g][wv2][j][lane];
                        float* dst = out + (size_t)list[s] * OUTF + o0 + quad * 4;
                        *(float4*)dst = make_float4(a[0], a[1], a[2], a[3]);
                    }
                }
            }
        }
        __syncthreads();   // red reusable next chunk
    }
}

extern "C" void kernel_launch(void* const* d_in, const int* in_sizes, int n_in,
                              void* d_out, int out_size, void* d_ws, size_t ws_size,
                              hipStream_t stream) {
    const float* x   = (const float*)d_in[0];
    const int*   idx = (const int*)d_in[1];
    const float* w   = (const float*)d_in[2];
    float* out = (float*)d_out;

    switching_linear_kernel<<<dim3(NBLK), dim3(THREADS), 0, stream>>>(x, idx, w, out);
}

// Round 6
// 113.248 us; speedup vs baseline: 1.2629x; 1.0006x over previous
//
#include <hip/hip_runtime.h>

// out[b, o] = sum_k weight[index[b], o, k] * x[b, k];  B=2048, C=64, IN=OUT=512.
//
// r2-r5 all plateaued at ~40us / 1.3 TB/s. Common factor: W was read with
// 16-row x 2KB-stride gathers (MFMA A-frag wants 16 rows/quad) -> DRAM
// channel/row-buffer camping. Fix: a block's 16x512 W-tile is a CONTIGUOUS
// 32KB region; stage it with 32 global_load_lds dwordx4 insts, each a
// contiguous 1KB half-row (16B-granule XOR swizzle applied on the *source*
// side, within 128B lines -> coalescing identical to a linear copy).
// Compute reads A-frags from LDS as ds_read_b128 (swizzle -> minimal bank
// serialization). Everything else = r5: grid 2048 (class x 32 row-tiles),
// wave = K-quarter, x gathered from L3, LDS K-reduce, deterministic.

constexpr int Bsz  = 2048;
constexpr int Ccnt = 64;
constexpr int INF  = 512;
constexpr int OUTF = 512;
constexpr int THREADS = 256;   // 4 waves = 4 K-quarters
constexpr int OT = 16;         // out rows per block
constexpr int NBLK = Ccnt * (OUTF / OT);   // 2048

typedef __attribute__((ext_vector_type(8))) short bf16x8;
typedef __attribute__((ext_vector_type(4))) float f32x4;

#if __has_builtin(__builtin_amdgcn_cvt_pk_bf16_f32)
typedef __attribute__((ext_vector_type(2))) __bf16 bf16x2_t;
__device__ __forceinline__ int cvt2i(float a, float b) {
    union { bf16x2_t v; int i; } u;
    u.v = __builtin_amdgcn_cvt_pk_bf16_f32(a, b);
    return u.i;
}
#else
__device__ __forceinline__ unsigned f2bf(float f) {
    union { float f; unsigned u; } v; v.f = f;
    return (v.u + 0x7FFFu + ((v.u >> 16) & 1u)) >> 16;   // RNE
}
__device__ __forceinline__ int cvt2i(float a, float b) {
    return (int)(f2bf(a) | (f2bf(b) << 16));
}
#endif

__device__ __forceinline__ bf16x8 cvt8(float4 a, float4 b) {
    union { bf16x8 v; int i[4]; } u;
    u.i[0] = cvt2i(a.x, a.y);
    u.i[1] = cvt2i(a.z, a.w);
    u.i[2] = cvt2i(b.x, b.y);
    u.i[3] = cvt2i(b.z, b.w);
    return u.v;
}

// async 16B/lane global -> LDS (dest = wave-uniform base + lane*16)
__device__ __forceinline__ void gld_lds16(const float* g, float* l) {
    __builtin_amdgcn_global_load_lds(
        (const __attribute__((address_space(1))) float*)g,
        (__attribute__((address_space(3))) float*)l, 16, 0, 0);
}

__global__ __launch_bounds__(THREADS, 3)
void switching_linear_kernel(const float* __restrict__ x,
                             const int* __restrict__ idx,
                             const float* __restrict__ w,
                             float* __restrict__ out) {
    __shared__ float Wl[OT * INF];          // 32 KB, XOR-swizzled row-major
    __shared__ unsigned short list[Bsz];    // 4 KB
    __shared__ int ls_n;
    __shared__ float red[4][3][4][64];      // 12 KB, lane-major

    const int tid  = threadIdx.x;
    const int wave = tid >> 6;
    const int lane = tid & 63;
    const int c  = blockIdx.x >> 5;           // class
    const int o0 = (blockIdx.x & 31) * OT;    // out-row base

    if (tid == 0) ls_n = 0;
    __syncthreads();   // nothing in flight yet

    // ---- stage W tile: contiguous 32KB -> LDS, 32 x 1KB insts ----
    // Element (r,k) lands at Wl[r*512 + ((k>>2) ^ (r&7))*4 + (k&3)].
    // inst covers row r = inst>>1, half h = inst&1; source granule for dest
    // slot L is (h*64 + (L ^ (r&7)))  -> permutation within 128B lines only.
    const float* wc = w + (size_t)c * OUTF * INF + (size_t)o0 * INF;
#pragma unroll
    for (int i = 0; i < 8; ++i) {
        const int inst = wave * 8 + i;
        const int r = inst >> 1;
        const int h = inst & 1;
        const int p = r & 7;
        const float* src = wc + (size_t)r * INF + (h * 64 + (lane ^ p)) * 4;
        gld_lds16(src, &Wl[inst * 256]);
    }

    // ---- idx scan (overlaps W staging flight) ----
    int my[8];
#pragma unroll
    for (int i = 0; i < 8; ++i) my[i] = idx[tid + i * THREADS];
#pragma unroll
    for (int i = 0; i < 8; ++i)
        if (my[i] == c) list[atomicAdd(&ls_n, 1)] = (unsigned short)(tid + i * THREADS);

    __syncthreads();   // W in LDS + list complete
    const int n = ls_n;
    if (n == 0) return;

    const int mrow = lane & 15;   // A row / B col / C col
    const int quad = lane >> 4;   // k segment / C row group
    const int k0   = wave * (INF / 4);
    const int p    = mrow & 7;

    // ---- A-fragments from LDS (once; reused across all sample groups) ----
    bf16x8 wf[4];
#pragma unroll
    for (int t = 0; t < 4; ++t) {
        const int gb = (k0 >> 2) + t * 8 + quad * 2;   // granule index in row
        float4 a0 = *(const float4*)&Wl[mrow * INF + ((gb)     ^ p) * 4];
        float4 a1 = *(const float4*)&Wl[mrow * INF + ((gb + 1) ^ p) * 4];
        wf[t] = cvt8(a0, a1);
    }

    for (int s0 = 0; s0 < n; s0 += 64) {
        const int rem = n - s0;
        const int ng  = rem >= 64 ? 4 : (rem + 15) >> 4;

        f32x4 acc[4];
#pragma unroll
        for (int g = 0; g < 4; ++g) acc[g] = (f32x4){0.f, 0.f, 0.f, 0.f};

#pragma unroll 2
        for (int g = 0; g < ng; ++g) {
            const int s = s0 + g * 16 + mrow;
            const bool v = (s < n);
            const float* bp = x + (size_t)(v ? (int)list[s] : 0) * INF + k0 + quad * 8;
            bf16x8 xf[4];
            if (v) {
#pragma unroll
                for (int i = 0; i < 4; ++i) {
                    float4 b0 = *(const float4*)(bp + i * 32);
                    float4 b1 = *(const float4*)(bp + i * 32 + 4);
                    xf[i] = cvt8(b0, b1);
                }
            } else {
#pragma unroll
                for (int i = 0; i < 4; ++i) xf[i] = (bf16x8){0,0,0,0,0,0,0,0};
            }
#pragma unroll
            for (int i = 0; i < 4; ++i)
                acc[g] = __builtin_amdgcn_mfma_f32_16x16x32_bf16(wf[i], xf[i], acc[g], 0, 0, 0);
        }

        // ---- K-reduce across 4 waves (fixed order -> deterministic) ----
        if (wave != 0) {
#pragma unroll
            for (int g = 0; g < 4; ++g) {
                if (g < ng) {
#pragma unroll
                    for (int j = 0; j < 4; ++j) red[g][wave - 1][j][lane] = acc[g][j];
                }
            }
        }
        __syncthreads();
        if (wave == 0) {
#pragma unroll
            for (int g = 0; g < 4; ++g) {
                if (g < ng) {
                    const int s = s0 + g * 16 + mrow;
                    if (s < n) {
                        f32x4 a = acc[g];
#pragma unroll
                        for (int wv2 = 0; wv2 < 3; ++wv2)
#pragma unroll
                            for (int j = 0; j < 4; ++j) a[j] += red[g][wv2][j][lane];
                        float* dst = out + (size_t)list[s] * OUTF + o0 + quad * 4;
                        *(float4*)dst = make_float4(a[0], a[1], a[2], a[3]);
                    }
                }
            }
        }
        __syncthreads();   // red reusable next chunk
    }
}

extern "C" void kernel_launch(void* const* d_in, const int* in_sizes, int n_in,
                              void* d_out, int out_size, void* d_ws, size_t ws_size,
                              hipStream_t stream) {
    const float* x   = (const float*)d_in[0];
    const int*   idx = (const int*)d_in[1];
    const float* w   = (const float*)d_in[2];
    float* out = (float*)d_out;

    switching_linear_kernel<<<dim3(NBLK), dim3(THREADS), 0, stream>>>(x, idx, w, out);
}